// Round 10
// baseline (152.346 us; speedup 1.0000x reference)
//
#include <hip/hip_runtime.h>
#include <stdint.h>

#define DM    768
#define NH    12
#define HD    64
#define BATCH 4
#define SEQ   2048
#define NTOK  (BATCH*SEQ)   // 8192
#define NKT   12            // 768 / 64 K-tiles

typedef unsigned int   u32;
typedef unsigned short u16;
using bf16x8 = __attribute__((ext_vector_type(8))) short;
using f32x4  = __attribute__((ext_vector_type(4))) float;

// softmax runs in exp2 domain: Q pre-scaled by (1/8)*log2(e)
#define QSCALE 0.18033688011112042f

__device__ __forceinline__ u16 f2bf(float f) {
    u32 u = __float_as_uint(f);
    u = (u + 0x7FFFu + ((u >> 16) & 1u)) >> 16;
    return (u16)u;
}

__device__ __forceinline__ u32 pkbf(float a, float b) {
    u32 r;
    asm("v_cvt_pk_bf16_f32 %0, %1, %2" : "=v"(r) : "v"(a), "v"(b));
    return r;
}

template <int N>
__device__ __forceinline__ void waitvm() {
    if constexpr (N == 0)      asm volatile("s_waitcnt vmcnt(0)" ::: "memory");
    else if constexpr (N == 5) asm volatile("s_waitcnt vmcnt(5)" ::: "memory");
    else if constexpr (N == 8) asm volatile("s_waitcnt vmcnt(8)" ::: "memory");
    else if constexpr (N == 9) asm volatile("s_waitcnt vmcnt(9)" ::: "memory");
    else                       static_assert(N == 0 || N == 5 || N == 8 || N == 9, "add literal");
}

__device__ __forceinline__ void gload_lds16(const void* gptr, void* ldsptr) {
    __builtin_amdgcn_global_load_lds(
        (__attribute__((address_space(1))) const u32*)gptr,
        (__attribute__((address_space(3))) u32*)ldsptr, 16, 0, 0);
}

__device__ __forceinline__ float vmax4(f32x4 v) {
    return fmaxf(fmaxf(v[0], v[1]), fmaxf(v[2], v[3]));
}

// ---------------- x fp32 -> bf16 (vectorized) ----------------
__global__ void cvt_x(const float* __restrict__ x, u16* __restrict__ xb, int n4) {
    int i = blockIdx.x * blockDim.x + threadIdx.x;
    if (i >= n4) return;
    float4 v = ((const float4*)x)[i];
    ushort4 o;
    o.x = f2bf(v.x); o.y = f2bf(v.y); o.z = f2bf(v.z); o.w = f2bf(v.w);
    ((ushort4*)xb)[i] = o;
}

// ------- all 4 weight transposes in ONE launch: W [k][n] fp32 -> Wt [n][k] bf16 -------
__global__ void transpose_w4(const float* __restrict__ q, const float* __restrict__ k,
                             const float* __restrict__ v, const float* __restrict__ o,
                             u16* __restrict__ Wt, u16* __restrict__ Wto) {
    __shared__ float tile[32][33];
    int z = blockIdx.z;
    const float* W = (z == 0) ? q : (z == 1) ? k : (z == 2) ? v : o;
    u16* D = (z < 3) ? (Wt + (size_t)z * DM * DM) : Wto;
    int tx = threadIdx.x, ty = threadIdx.y;   // 32 x 8
    int x0 = blockIdx.x * 32, y0 = blockIdx.y * 32;
    #pragma unroll
    for (int i = 0; i < 32; i += 8)
        tile[ty + i][tx] = W[(size_t)(y0 + ty + i) * DM + x0 + tx];
    __syncthreads();
    #pragma unroll
    for (int i = 0; i < 32; i += 8)
        D[(size_t)(x0 + ty + i) * DM + y0 + tx] = f2bf(tile[tx][ty + i]);
}

// ---- bf16 MFMA GEMM, BK=64, 2-tiles-ahead pipeline with counted vmcnt (T3/T4) ----
// (unchanged — MODE0 grid 32x8=256 blocks, MODE1 64x4=256 blocks)
template <int MODE>
__global__ __launch_bounds__(512, 2)
void gemm_pipe(const u16* __restrict__ A, const u16* __restrict__ Bt,
               const float* __restrict__ b0, const float* __restrict__ b1,
               const float* __restrict__ b2,
               u16* __restrict__ Qo, u16* __restrict__ Ko, u16* __restrict__ Vto,
               float* __restrict__ Out)
{
    constexpr int BM = (MODE == 0) ? 256 : 128;
    constexpr int BN = (MODE == 0) ? 288 : 192;
    constexpr int MF = 4;
    constexpr int NF = (MODE == 0) ? 9 : 3;
    constexpr int AL = BM / 64;
    constexpr int BFULL = (MODE == 0) ? 4 : 3;

    __shared__ u16 As[2][BM][64];
    __shared__ u16 Bs[2][BN][64];

    const int t = threadIdx.x;
    const int w = t >> 6, l = t & 63;
    const int l15 = l & 15, lg = l >> 4;
    const int m0 = blockIdx.x * BM;
    const int n0 = blockIdx.y * BN;
    const int waveM = ((MODE == 0) ? (w >> 1) : (w >> 2)) * 64;
    const int waveN = (MODE == 0) ? (w & 1) * 144 : (w & 3) * 48;

    f32x4 zf = {0.f, 0.f, 0.f, 0.f};
    f32x4 acc[MF][NF];
    #pragma unroll
    for (int i = 0; i < MF; ++i)
        #pragma unroll
        for (int j = 0; j < NF; ++j) acc[i][j] = zf;

    const u16* Arow0 = A  + (size_t)m0 * DM;
    const u16* Brow0 = Bt + (size_t)n0 * DM;

    auto stage = [&](int d, int k0) {
        #pragma unroll
        for (int i = 0; i < AL; ++i) {
            int f = i * 512 + t;
            int row = f >> 3, c = f & 7;
            int gc = c ^ (row & 7);
            gload_lds16(Arow0 + (size_t)row * DM + k0 + gc * 8, &As[d][row][c * 8]);
        }
        #pragma unroll
        for (int i = 0; i < BFULL; ++i) {
            int f = i * 512 + t;
            int row = f >> 3, c = f & 7;
            int gc = c ^ (row & 7);
            gload_lds16(Brow0 + (size_t)row * DM + k0 + gc * 8, &Bs[d][row][c * 8]);
        }
        if constexpr (MODE == 0) {
            if (t < 256) {
                int f = 2048 + t;
                int row = f >> 3, c = f & 7;
                int gc = c ^ (row & 7);
                gload_lds16(Brow0 + (size_t)row * DM + k0 + gc * 8, &Bs[d][row][c * 8]);
            }
        }
    };
    auto wait_tile = [&]() {
        if constexpr (MODE == 0) {
            if (w < 4) waitvm<9>(); else waitvm<8>();
        } else {
            waitvm<5>();
        }
    };
    auto phase = [&](int d, int kk) {
        const int ch = ((kk * 4 + lg) ^ (l15 & 7)) * 8;
        bf16x8 af[MF], bfr[NF];
        #pragma unroll
        for (int m = 0; m < MF; ++m)
            af[m] = *(const bf16x8*)&As[d][waveM + m * 16 + l15][ch];
        #pragma unroll
        for (int n = 0; n < NF; ++n)
            bfr[n] = *(const bf16x8*)&Bs[d][waveN + n * 16 + l15][ch];
        __builtin_amdgcn_s_setprio(1);
        #pragma unroll
        for (int m = 0; m < MF; ++m)
            #pragma unroll
            for (int n = 0; n < NF; ++n)
                acc[m][n] = __builtin_amdgcn_mfma_f32_16x16x32_bf16(af[m], bfr[n], acc[m][n], 0, 0, 0);
        __builtin_amdgcn_s_setprio(0);
    };

    stage(0, 0);
    stage(1, 64);

    for (int tt = 0; tt < NKT - 1; ++tt) {
        const int c = tt & 1;
        wait_tile();
        __builtin_amdgcn_s_barrier();
        __builtin_amdgcn_sched_barrier(0);
        phase(c, 0);
        phase(c, 1);
        __builtin_amdgcn_sched_barrier(0);
        __builtin_amdgcn_s_barrier();
        __builtin_amdgcn_sched_barrier(0);
        if (tt + 2 < NKT) stage(c, (tt + 2) * 64);
    }
    {
        waitvm<0>();
        __builtin_amdgcn_s_barrier();
        __builtin_amdgcn_sched_barrier(0);
        phase((NKT - 1) & 1, 0);
        phase((NKT - 1) & 1, 1);
    }

    if (MODE == 1) {
        #pragma unroll
        for (int m = 0; m < MF; ++m) {
            int grow = m0 + waveM + m * 16 + lg * 4;
            #pragma unroll
            for (int n = 0; n < NF; ++n) {
                int gcol = n0 + waveN + n * 16 + l15;
                float bias = b0[gcol];
                #pragma unroll
                for (int r = 0; r < 4; ++r)
                    Out[(size_t)(grow + r) * DM + gcol] = acc[m][n][r] + bias;
            }
        }
    } else {
        #pragma unroll
        for (int m = 0; m < MF; ++m) {
            int grow = m0 + waveM + m * 16 + lg * 4;
            int bb = grow >> 11, ss = grow & 2047;
            #pragma unroll
            for (int n = 0; n < NF; ++n) {
                int nstart = n0 + waveN + n * 16;
                int which = nstart / DM;
                int cbase = nstart - which * DM + l15;
                int h = cbase >> 6, hd = cbase & 63;
                if (which == 0) {
                    float bias = b0[cbase];
                    #pragma unroll
                    for (int r = 0; r < 4; ++r)
                        Qo[(((size_t)bb * NH + h) * SEQ + (ss + r)) * HD + hd] =
                            f2bf((acc[m][n][r] + bias) * QSCALE);
                } else if (which == 1) {
                    float bias = b1[cbase];
                    #pragma unroll
                    for (int r = 0; r < 4; ++r)
                        Ko[(((size_t)bb * NH + h) * SEQ + (ss + r)) * HD + hd] =
                            f2bf(acc[m][n][r] + bias);
                } else {
                    float bias = b2[cbase];
                    u32 lo = pkbf(acc[m][n][0] + bias, acc[m][n][1] + bias);
                    u32 hi = pkbf(acc[m][n][2] + bias, acc[m][n][3] + bias);
                    *(int2*)&Vto[(((size_t)bb * NH + h) * HD + hd) * SEQ + ss] =
                        make_int2((int)lo, (int)hi);
                }
            }
        }
    }
}

// ---------------- causal flash attention v5 ----------------
// KV macro-tile = 128 keys per barrier (two sequential 64-key halves reusing
// the same registers): staging, write-late, barrier, loop control all halve
// per unit work; early-issued loads get a 2x compute window.
// Swizzled unpadded LDS (chunk c of row r at c ^ (r&7)); exp2-domain softmax,
// defer-max, v3 ordering (li reduce before PV).
__global__ __launch_bounds__(512, 4)
void attn_fwd(const u16* __restrict__ Q, const u16* __restrict__ K_,
              const u16* __restrict__ Vt, u16* __restrict__ ctx)
{
    __shared__ u16 Ks[2][128][64];      // [key][d]
    __shared__ u16 Vs[2][64][128];      // [d][key]

    const int t = threadIdx.x, w = t >> 6, l = t & 63;
    const int l15 = l & 15, lg = l >> 4;
    const int sw = l15 & 7;             // read-side swizzle key
    const int bx = blockIdx.x;
    const int ord = bx / 48;            // ascending => q8 descending (LPT dispatch)
    const int bh  = bx - ord * 48;
    const int q8  = 7 - ord;            // 256-row block index
    const int b = bh / NH, h = bh - b * NH;
    const int wrow0 = q8 * 256 + w * 32;
    const int niter = 2 * q8 + 2;       // 128-key macro-tiles

    const u16* Qp0 = Q + ((size_t)bh * SEQ + wrow0 + l15) * HD;
    const u16* Qp1 = Qp0 + 16 * HD;
    bf16x8 qf00 = *(const bf16x8*)(Qp0 + lg * 8);
    bf16x8 qf01 = *(const bf16x8*)(Qp0 + 32 + lg * 8);
    bf16x8 qf10 = *(const bf16x8*)(Qp1 + lg * 8);
    bf16x8 qf11 = *(const bf16x8*)(Qp1 + 32 + lg * 8);

    f32x4 zf = {0.f, 0.f, 0.f, 0.f};
    f32x4 acc0[4], acc1[4];
    #pragma unroll
    for (int d = 0; d < 4; ++d) { acc0[d] = zf; acc1[d] = zf; }
    float mi0 = -INFINITY, li0 = 0.f;
    float mi1 = -INFINITY, li1 = 0.f;

    const u16* Kbh = K_ + (size_t)bh * SEQ * HD;
    const u16* Vbh = Vt + (size_t)bh * HD * SEQ;
    // staging coords: K tile 128x64 (1024 int4, 2/thread), V tile 64x128 (2/thread)
    const int rk = t >> 3, ck = t & 7;              // K rows rk, rk+64
    const int rv = t >> 4, cv = t & 15;             // V rows rv, rv+32
    const int kw0 = (ck ^ (rk & 7)) * 8;
    const int kw1 = (ck ^ ((rk + 64) & 7)) * 8;
    const int vw0 = ((cv ^ (rv & 7)) & 15) * 8;     // XOR affects low 3 bits only
    const int vw1 = ((cv ^ ((rv + 32) & 7)) & 15) * 8;

    {   // prologue: stage macro-tile 0 (keys 0..127)
        int4 k0r = *(const int4*)(Kbh + (size_t)rk * HD + ck * 8);
        int4 k1r = *(const int4*)(Kbh + (size_t)(rk + 64) * HD + ck * 8);
        int4 v0r = *(const int4*)(Vbh + (size_t)rv * SEQ + cv * 8);
        int4 v1r = *(const int4*)(Vbh + (size_t)(rv + 32) * SEQ + cv * 8);
        *(int4*)&Ks[0][rk][kw0]      = k0r;
        *(int4*)&Ks[0][rk + 64][kw1] = k1r;
        *(int4*)&Vs[0][rv][vw0]      = v0r;
        *(int4*)&Vs[0][rv + 32][vw1] = v1r;
    }
    __syncthreads();

    for (int jt = 0; jt < niter; ++jt) {
        const int cur = jt & 1;
        const int j0 = jt << 7;
        int4 kn0, kn1, vn0, vn1;
        if (jt < niter - 1) {           // issue next macro-tile loads early
            int j1 = j0 + 128;
            kn0 = *(const int4*)(Kbh + (size_t)(j1 + rk) * HD + ck * 8);
            kn1 = *(const int4*)(Kbh + (size_t)(j1 + rk + 64) * HD + ck * 8);
            vn0 = *(const int4*)(Vbh + (size_t)rv * SEQ + j1 + cv * 8);
            vn1 = *(const int4*)(Vbh + (size_t)(rv + 32) * SEQ + j1 + cv * 8);
        }
        const u16 (*Kc)[64]  = Ks[cur];
        const u16 (*Vc)[128] = Vs[cur];
        #pragma unroll
        for (int hk = 0; hk < 2; ++hk) {
            const int j0h = j0 + hk * 64;
            if (j0h <= wrow0 + 31) {    // wave-uniform causal skip per half
                f32x4 s0[4], s1[4];
                __builtin_amdgcn_s_setprio(1);
                #pragma unroll
                for (int nt = 0; nt < 4; ++nt) {
                    const u16* krow = Kc[hk * 64 + nt * 16 + l15];
                    bf16x8 kf0 = *(const bf16x8*)&krow[(lg ^ sw) * 8];
                    bf16x8 kf1 = *(const bf16x8*)&krow[((4 + lg) ^ sw) * 8];
                    f32x4 a = zf;
                    a = __builtin_amdgcn_mfma_f32_16x16x32_bf16(kf0, qf00, a, 0, 0, 0);
                    a = __builtin_amdgcn_mfma_f32_16x16x32_bf16(kf1, qf01, a, 0, 0, 0);
                    s0[nt] = a;
                    f32x4 c2 = zf;
                    c2 = __builtin_amdgcn_mfma_f32_16x16x32_bf16(kf0, qf10, c2, 0, 0, 0);
                    c2 = __builtin_amdgcn_mfma_f32_16x16x32_bf16(kf1, qf11, c2, 0, 0, 0);
                    s1[nt] = c2;
                }
                __builtin_amdgcn_s_setprio(0);
                if (j0h + 63 > wrow0) { // diagonal region: per-element causal mask
                    #pragma unroll
                    for (int nt = 0; nt < 4; ++nt) {
                        int kb = j0h + nt * 16 + lg * 4;
                        #pragma unroll
                        for (int r = 0; r < 4; ++r) {
                            if (kb + r > wrow0 + l15)      s0[nt][r] = -INFINITY;
                            if (kb + r > wrow0 + 16 + l15) s1[nt][r] = -INFINITY;
                        }
                    }
                }
                float pm0 = fmaxf(fmaxf(vmax4(s0[0]), vmax4(s0[1])), fmaxf(vmax4(s0[2]), vmax4(s0[3])));
                float pm1 = fmaxf(fmaxf(vmax4(s1[0]), vmax4(s1[1])), fmaxf(vmax4(s1[2]), vmax4(s1[3])));
                pm0 = fmaxf(pm0, __shfl_xor(pm0, 16)); pm0 = fmaxf(pm0, __shfl_xor(pm0, 32));
                pm1 = fmaxf(pm1, __shfl_xor(pm1, 16)); pm1 = fmaxf(pm1, __shfl_xor(pm1, 32));
                if (!__all((pm0 <= mi0 + 8.f) && (pm1 <= mi1 + 8.f))) {
                    float mn0 = fmaxf(mi0, pm0), mn1 = fmaxf(mi1, pm1);
                    float so0 = __builtin_amdgcn_exp2f(mi0 - mn0);
                    float so1 = __builtin_amdgcn_exp2f(mi1 - mn1);
                    mi0 = mn0; mi1 = mn1;
                    li0 *= so0; li1 *= so1;
                    float a0 = __shfl(so0, lg * 4 + 0), a1 = __shfl(so0, lg * 4 + 1);
                    float a2 = __shfl(so0, lg * 4 + 2), a3 = __shfl(so0, lg * 4 + 3);
                    float b0_ = __shfl(so1, lg * 4 + 0), b1_ = __shfl(so1, lg * 4 + 1);
                    float b2_ = __shfl(so1, lg * 4 + 2), b3_ = __shfl(so1, lg * 4 + 3);
                    #pragma unroll
                    for (int d = 0; d < 4; ++d) {
                        acc0[d][0] *= a0;  acc0[d][1] *= a1;  acc0[d][2] *= a2;  acc0[d][3] *= a3;
                        acc1[d][0] *= b0_; acc1[d][1] *= b1_; acc1[d][2] *= b2_; acc1[d][3] *= b3_;
                    }
                }
                u32 dwa[8], dwb[8];
                float rs0 = 0.f, rs1 = 0.f;
                #pragma unroll
                for (int nt = 0; nt < 4; ++nt) {
                    float p0 = __builtin_amdgcn_exp2f(s0[nt][0] - mi0);
                    float p1 = __builtin_amdgcn_exp2f(s0[nt][1] - mi0);
                    float p2 = __builtin_amdgcn_exp2f(s0[nt][2] - mi0);
                    float p3 = __builtin_amdgcn_exp2f(s0[nt][3] - mi0);
                    rs0 += (p0 + p1) + (p2 + p3);
                    dwa[nt * 2] = pkbf(p0, p1); dwa[nt * 2 + 1] = pkbf(p2, p3);
                    float q0 = __builtin_amdgcn_exp2f(s1[nt][0] - mi1);
                    float q1 = __builtin_amdgcn_exp2f(s1[nt][1] - mi1);
                    float q2 = __builtin_amdgcn_exp2f(s1[nt][2] - mi1);
                    float q3 = __builtin_amdgcn_exp2f(s1[nt][3] - mi1);
                    rs1 += (q0 + q1) + (q2 + q3);
                    dwb[nt * 2] = pkbf(q0, q1); dwb[nt * 2 + 1] = pkbf(q2, q3);
                }
                rs0 += __shfl_xor(rs0, 16); rs0 += __shfl_xor(rs0, 32);
                rs1 += __shfl_xor(rs1, 16); rs1 += __shfl_xor(rs1, 32);
                li0 += rs0; li1 += rs1;
                bf16x8 pa00 = __builtin_bit_cast(bf16x8, make_int4((int)dwa[0], (int)dwa[1], (int)dwa[2], (int)dwa[3]));
                bf16x8 pa01 = __builtin_bit_cast(bf16x8, make_int4((int)dwa[4], (int)dwa[5], (int)dwa[6], (int)dwa[7]));
                bf16x8 pa10 = __builtin_bit_cast(bf16x8, make_int4((int)dwb[0], (int)dwb[1], (int)dwb[2], (int)dwb[3]));
                bf16x8 pa11 = __builtin_bit_cast(bf16x8, make_int4((int)dwb[4], (int)dwb[5], (int)dwb[6], (int)dwb[7]));
                // O += P V  (swizzled int2 V reads from half hk)
                const int o4 = (lg & 1) * 4, c0 = lg >> 1;
                __builtin_amdgcn_s_setprio(1);
                #pragma unroll
                for (int d = 0; d < 4; ++d) {
                    const u16* vrow = Vc[d * 16 + l15] + hk * 64;
                    int2 v0 = *(const int2*)(vrow + (((c0 + 0) ^ sw) * 8 + o4));
                    int2 v1 = *(const int2*)(vrow + (((c0 + 2) ^ sw) * 8 + o4));
                    int2 v2 = *(const int2*)(vrow + (((c0 + 4) ^ sw) * 8 + o4));
                    int2 v3 = *(const int2*)(vrow + (((c0 + 6) ^ sw) * 8 + o4));
                    bf16x8 vf0 = __builtin_bit_cast(bf16x8, make_int4(v0.x, v0.y, v1.x, v1.y));
                    bf16x8 vf1 = __builtin_bit_cast(bf16x8, make_int4(v2.x, v2.y, v3.x, v3.y));
                    acc0[d] = __builtin_amdgcn_mfma_f32_16x16x32_bf16(pa00, vf0, acc0[d], 0, 0, 0);
                    acc0[d] = __builtin_amdgcn_mfma_f32_16x16x32_bf16(pa01, vf1, acc0[d], 0, 0, 0);
                    acc1[d] = __builtin_amdgcn_mfma_f32_16x16x32_bf16(pa10, vf0, acc1[d], 0, 0, 0);
                    acc1[d] = __builtin_amdgcn_mfma_f32_16x16x32_bf16(pa11, vf1, acc1[d], 0, 0, 0);
                }
                __builtin_amdgcn_s_setprio(0);
            }
        }
        if (jt < niter - 1) {           // write-late into the other buffer
            *(int4*)&Ks[cur ^ 1][rk][kw0]      = kn0;
            *(int4*)&Ks[cur ^ 1][rk + 64][kw1] = kn1;
            *(int4*)&Vs[cur ^ 1][rv][vw0]      = vn0;
            *(int4*)&Vs[cur ^ 1][rv + 32][vw1] = vn1;
        }
        __syncthreads();
    }

    float e00 = 1.0f / __shfl(li0, lg * 4 + 0), e01 = 1.0f / __shfl(li0, lg * 4 + 1);
    float e02 = 1.0f / __shfl(li0, lg * 4 + 2), e03 = 1.0f / __shfl(li0, lg * 4 + 3);
    float e10 = 1.0f / __shfl(li1, lg * 4 + 0), e11 = 1.0f / __shfl(li1, lg * 4 + 1);
    float e12 = 1.0f / __shfl(li1, lg * 4 + 2), e13 = 1.0f / __shfl(li1, lg * 4 + 3);
    #pragma unroll
    for (int r = 0; r < 4; ++r) {
        float f0 = (r == 0) ? e00 : (r == 1) ? e01 : (r == 2) ? e02 : e03;
        float f1 = (r == 0) ? e10 : (r == 1) ? e11 : (r == 2) ? e12 : e13;
        int s0r = wrow0 + lg * 4 + r;
        size_t base0 = ((size_t)b * SEQ + s0r) * DM + h * HD;
        size_t base1 = ((size_t)b * SEQ + s0r + 16) * DM + h * HD;
        #pragma unroll
        for (int d = 0; d < 4; ++d) {
            ctx[base0 + d * 16 + l15] = f2bf(acc0[d][r] * f0);
            ctx[base1 + d * 16 + l15] = f2bf(acc1[d][r] * f1);
        }
    }
}

extern "C" void kernel_launch(void* const* d_in, const int* in_sizes, int n_in,
                              void* d_out, int out_size, void* d_ws, size_t ws_size,
                              hipStream_t stream) {
    const float* x  = (const float*)d_in[0];
    const float* Wq = (const float*)d_in[1];
    const float* bq = (const float*)d_in[2];
    const float* Wk = (const float*)d_in[3];
    const float* bk = (const float*)d_in[4];
    const float* Wv = (const float*)d_in[5];
    const float* bv = (const float*)d_in[6];
    const float* Wo = (const float*)d_in[7];
    const float* bo = (const float*)d_in[8];
    float* out = (float*)d_out;

    char* ws = (char*)d_ws;
    u16* xb  = (u16*)(ws);                    // 8192*768*2      = 12,582,912
    u16* Wt  = (u16*)(ws + 12582912);         // 2304*768*2      =  3,538,944
    u16* Wto = (u16*)(ws + 16121856);         // 768*768*2       =  1,179,648
    u16* Qw  = (u16*)(ws + 17301504);         // [BH][S][64]     = 12,582,912
    u16* Kw  = (u16*)(ws + 29884416);         // [BH][S][64]     = 12,582,912
    u16* Vtw = (u16*)(ws + 42467328);         // [BH][64][S]     = 12,582,912
    u16* ctx = (u16*)(ws + 55050240);         // [B][S][768]     = 12,582,912

    cvt_x<<<6144, 256, 0, stream>>>(x, xb, NTOK * DM / 4);
    dim3 tb(32, 8), tg4(24, 24, 4);
    transpose_w4<<<tg4, tb, 0, stream>>>(Wq, Wk, Wv, Wo, Wt, Wto);

    dim3 g2(32, 8);
    gemm_pipe<0><<<g2, 512, 0, stream>>>(xb, Wt, bq, bk, bv, Qw, Kw, Vtw, nullptr);
    attn_fwd<<<384, 512, 0, stream>>>(Qw, Kw, Vtw, ctx);
    dim3 g4(64, 4);
    gemm_pipe<1><<<g4, 512, 0, stream>>>(ctx, Wto, bo, nullptr, nullptr, nullptr, nullptr, nullptr, out);
}

// Round 11
// 126.595 us; speedup vs baseline: 1.2034x; 1.2034x over previous
//
#include <hip/hip_runtime.h>
#include <stdint.h>

#define DM    768
#define NH    12
#define HD    64
#define BATCH 4
#define SEQ   2048
#define NTOK  (BATCH*SEQ)   // 8192
#define NKT   12            // 768 / 64 K-tiles

typedef unsigned int   u32;
typedef unsigned short u16;
using bf16x8 = __attribute__((ext_vector_type(8))) short;
using f32x4  = __attribute__((ext_vector_type(4))) float;

// softmax runs in exp2 domain: Q pre-scaled by (1/8)*log2(e)
#define QSCALE 0.18033688011112042f

__device__ __forceinline__ u16 f2bf(float f) {
    u32 u = __float_as_uint(f);
    u = (u + 0x7FFFu + ((u >> 16) & 1u)) >> 16;
    return (u16)u;
}

__device__ __forceinline__ u32 pkbf(float a, float b) {
    u32 r;
    asm("v_cvt_pk_bf16_f32 %0, %1, %2" : "=v"(r) : "v"(a), "v"(b));
    return r;
}

template <int N>
__device__ __forceinline__ void waitvm() {
    if constexpr (N == 0)      asm volatile("s_waitcnt vmcnt(0)" ::: "memory");
    else if constexpr (N == 5) asm volatile("s_waitcnt vmcnt(5)" ::: "memory");
    else if constexpr (N == 8) asm volatile("s_waitcnt vmcnt(8)" ::: "memory");
    else if constexpr (N == 9) asm volatile("s_waitcnt vmcnt(9)" ::: "memory");
    else                       static_assert(N == 0 || N == 5 || N == 8 || N == 9, "add literal");
}

__device__ __forceinline__ void gload_lds16(const void* gptr, void* ldsptr) {
    __builtin_amdgcn_global_load_lds(
        (__attribute__((address_space(1))) const u32*)gptr,
        (__attribute__((address_space(3))) u32*)ldsptr, 16, 0, 0);
}

__device__ __forceinline__ float vmax4(f32x4 v) {
    return fmaxf(fmaxf(v[0], v[1]), fmaxf(v[2], v[3]));
}

// ---------------- x fp32 -> bf16 (vectorized) ----------------
__global__ void cvt_x(const float* __restrict__ x, u16* __restrict__ xb, int n4) {
    int i = blockIdx.x * blockDim.x + threadIdx.x;
    if (i >= n4) return;
    float4 v = ((const float4*)x)[i];
    ushort4 o;
    o.x = f2bf(v.x); o.y = f2bf(v.y); o.z = f2bf(v.z); o.w = f2bf(v.w);
    ((ushort4*)xb)[i] = o;
}

// ------- all 4 weight transposes in ONE launch: W [k][n] fp32 -> Wt [n][k] bf16 -------
__global__ void transpose_w4(const float* __restrict__ q, const float* __restrict__ k,
                             const float* __restrict__ v, const float* __restrict__ o,
                             u16* __restrict__ Wt, u16* __restrict__ Wto) {
    __shared__ float tile[32][33];
    int z = blockIdx.z;
    const float* W = (z == 0) ? q : (z == 1) ? k : (z == 2) ? v : o;
    u16* D = (z < 3) ? (Wt + (size_t)z * DM * DM) : Wto;
    int tx = threadIdx.x, ty = threadIdx.y;   // 32 x 8
    int x0 = blockIdx.x * 32, y0 = blockIdx.y * 32;
    #pragma unroll
    for (int i = 0; i < 32; i += 8)
        tile[ty + i][tx] = W[(size_t)(y0 + ty + i) * DM + x0 + tx];
    __syncthreads();
    #pragma unroll
    for (int i = 0; i < 32; i += 8)
        D[(size_t)(x0 + ty + i) * DM + y0 + tx] = f2bf(tile[tx][ty + i]);
}

// ---- bf16 MFMA GEMM, BK=64, 2-tiles-ahead pipeline with counted vmcnt (T3/T4) ----
// (unchanged — MODE0 grid 32x8=256 blocks, MODE1 64x4=256 blocks)
template <int MODE>
__global__ __launch_bounds__(512, 2)
void gemm_pipe(const u16* __restrict__ A, const u16* __restrict__ Bt,
               const float* __restrict__ b0, const float* __restrict__ b1,
               const float* __restrict__ b2,
               u16* __restrict__ Qo, u16* __restrict__ Ko, u16* __restrict__ Vto,
               float* __restrict__ Out)
{
    constexpr int BM = (MODE == 0) ? 256 : 128;
    constexpr int BN = (MODE == 0) ? 288 : 192;
    constexpr int MF = 4;
    constexpr int NF = (MODE == 0) ? 9 : 3;
    constexpr int AL = BM / 64;
    constexpr int BFULL = (MODE == 0) ? 4 : 3;

    __shared__ u16 As[2][BM][64];
    __shared__ u16 Bs[2][BN][64];

    const int t = threadIdx.x;
    const int w = t >> 6, l = t & 63;
    const int l15 = l & 15, lg = l >> 4;
    const int m0 = blockIdx.x * BM;
    const int n0 = blockIdx.y * BN;
    const int waveM = ((MODE == 0) ? (w >> 1) : (w >> 2)) * 64;
    const int waveN = (MODE == 0) ? (w & 1) * 144 : (w & 3) * 48;

    f32x4 zf = {0.f, 0.f, 0.f, 0.f};
    f32x4 acc[MF][NF];
    #pragma unroll
    for (int i = 0; i < MF; ++i)
        #pragma unroll
        for (int j = 0; j < NF; ++j) acc[i][j] = zf;

    const u16* Arow0 = A  + (size_t)m0 * DM;
    const u16* Brow0 = Bt + (size_t)n0 * DM;

    auto stage = [&](int d, int k0) {
        #pragma unroll
        for (int i = 0; i < AL; ++i) {
            int f = i * 512 + t;
            int row = f >> 3, c = f & 7;
            int gc = c ^ (row & 7);
            gload_lds16(Arow0 + (size_t)row * DM + k0 + gc * 8, &As[d][row][c * 8]);
        }
        #pragma unroll
        for (int i = 0; i < BFULL; ++i) {
            int f = i * 512 + t;
            int row = f >> 3, c = f & 7;
            int gc = c ^ (row & 7);
            gload_lds16(Brow0 + (size_t)row * DM + k0 + gc * 8, &Bs[d][row][c * 8]);
        }
        if constexpr (MODE == 0) {
            if (t < 256) {
                int f = 2048 + t;
                int row = f >> 3, c = f & 7;
                int gc = c ^ (row & 7);
                gload_lds16(Brow0 + (size_t)row * DM + k0 + gc * 8, &Bs[d][row][c * 8]);
            }
        }
    };
    auto wait_tile = [&]() {
        if constexpr (MODE == 0) {
            if (w < 4) waitvm<9>(); else waitvm<8>();
        } else {
            waitvm<5>();
        }
    };
    auto phase = [&](int d, int kk) {
        const int ch = ((kk * 4 + lg) ^ (l15 & 7)) * 8;
        bf16x8 af[MF], bfr[NF];
        #pragma unroll
        for (int m = 0; m < MF; ++m)
            af[m] = *(const bf16x8*)&As[d][waveM + m * 16 + l15][ch];
        #pragma unroll
        for (int n = 0; n < NF; ++n)
            bfr[n] = *(const bf16x8*)&Bs[d][waveN + n * 16 + l15][ch];
        __builtin_amdgcn_s_setprio(1);
        #pragma unroll
        for (int m = 0; m < MF; ++m)
            #pragma unroll
            for (int n = 0; n < NF; ++n)
                acc[m][n] = __builtin_amdgcn_mfma_f32_16x16x32_bf16(af[m], bfr[n], acc[m][n], 0, 0, 0);
        __builtin_amdgcn_s_setprio(0);
    };

    stage(0, 0);
    stage(1, 64);

    for (int tt = 0; tt < NKT - 1; ++tt) {
        const int c = tt & 1;
        wait_tile();
        __builtin_amdgcn_s_barrier();
        __builtin_amdgcn_sched_barrier(0);
        phase(c, 0);
        phase(c, 1);
        __builtin_amdgcn_sched_barrier(0);
        __builtin_amdgcn_s_barrier();
        __builtin_amdgcn_sched_barrier(0);
        if (tt + 2 < NKT) stage(c, (tt + 2) * 64);
    }
    {
        waitvm<0>();
        __builtin_amdgcn_s_barrier();
        __builtin_amdgcn_sched_barrier(0);
        phase((NKT - 1) & 1, 0);
        phase((NKT - 1) & 1, 1);
    }

    if (MODE == 1) {
        #pragma unroll
        for (int m = 0; m < MF; ++m) {
            int grow = m0 + waveM + m * 16 + lg * 4;
            #pragma unroll
            for (int n = 0; n < NF; ++n) {
                int gcol = n0 + waveN + n * 16 + l15;
                float bias = b0[gcol];
                #pragma unroll
                for (int r = 0; r < 4; ++r)
                    Out[(size_t)(grow + r) * DM + gcol] = acc[m][n][r] + bias;
            }
        }
    } else {
        #pragma unroll
        for (int m = 0; m < MF; ++m) {
            int grow = m0 + waveM + m * 16 + lg * 4;
            int bb = grow >> 11, ss = grow & 2047;
            #pragma unroll
            for (int n = 0; n < NF; ++n) {
                int nstart = n0 + waveN + n * 16;
                int which = nstart / DM;
                int cbase = nstart - which * DM + l15;
                int h = cbase >> 6, hd = cbase & 63;
                if (which == 0) {
                    float bias = b0[cbase];
                    #pragma unroll
                    for (int r = 0; r < 4; ++r)
                        Qo[(((size_t)bb * NH + h) * SEQ + (ss + r)) * HD + hd] =
                            f2bf((acc[m][n][r] + bias) * QSCALE);
                } else if (which == 1) {
                    float bias = b1[cbase];
                    #pragma unroll
                    for (int r = 0; r < 4; ++r)
                        Ko[(((size_t)bb * NH + h) * SEQ + (ss + r)) * HD + hd] =
                            f2bf(acc[m][n][r] + bias);
                } else {
                    float bias = b2[cbase];
                    u32 lo = pkbf(acc[m][n][0] + bias, acc[m][n][1] + bias);
                    u32 hi = pkbf(acc[m][n][2] + bias, acc[m][n][3] + bias);
                    *(int2*)&Vto[(((size_t)bb * NH + h) * HD + hd) * SEQ + ss] =
                        make_int2((int)lo, (int)hi);
                }
            }
        }
    }
}

// ---------------- causal flash attention v5b ----------------
// v5 (128-key macro-tile) with the launch-bounds fix: (512,2) not (512,4).
// R10's (512,4) forced a 64-VGPR budget -> ~50 regs spilled to scratch
// (WRITE_SIZE 12->42 MB, 91 us). LDS=64KB caps at 2 blocks/CU anyway.
__global__ __launch_bounds__(512, 2)
void attn_fwd(const u16* __restrict__ Q, const u16* __restrict__ K_,
              const u16* __restrict__ Vt, u16* __restrict__ ctx)
{
    __shared__ u16 Ks[2][128][64];      // [key][d]
    __shared__ u16 Vs[2][64][128];      // [d][key]

    const int t = threadIdx.x, w = t >> 6, l = t & 63;
    const int l15 = l & 15, lg = l >> 4;
    const int sw = l15 & 7;             // read-side swizzle key
    const int bx = blockIdx.x;
    const int ord = bx / 48;            // ascending => q8 descending (LPT dispatch)
    const int bh  = bx - ord * 48;
    const int q8  = 7 - ord;            // 256-row block index
    const int b = bh / NH, h = bh - b * NH;
    const int wrow0 = q8 * 256 + w * 32;
    const int niter = 2 * q8 + 2;       // 128-key macro-tiles

    const u16* Qp0 = Q + ((size_t)bh * SEQ + wrow0 + l15) * HD;
    const u16* Qp1 = Qp0 + 16 * HD;
    bf16x8 qf00 = *(const bf16x8*)(Qp0 + lg * 8);
    bf16x8 qf01 = *(const bf16x8*)(Qp0 + 32 + lg * 8);
    bf16x8 qf10 = *(const bf16x8*)(Qp1 + lg * 8);
    bf16x8 qf11 = *(const bf16x8*)(Qp1 + 32 + lg * 8);

    f32x4 zf = {0.f, 0.f, 0.f, 0.f};
    f32x4 acc0[4], acc1[4];
    #pragma unroll
    for (int d = 0; d < 4; ++d) { acc0[d] = zf; acc1[d] = zf; }
    float mi0 = -INFINITY, li0 = 0.f;
    float mi1 = -INFINITY, li1 = 0.f;

    const u16* Kbh = K_ + (size_t)bh * SEQ * HD;
    const u16* Vbh = Vt + (size_t)bh * HD * SEQ;
    // staging coords: K tile 128x64 (1024 int4, 2/thread), V tile 64x128 (2/thread)
    const int rk = t >> 3, ck = t & 7;              // K rows rk, rk+64
    const int rv = t >> 4, cv = t & 15;             // V rows rv, rv+32
    const int kw0 = (ck ^ (rk & 7)) * 8;
    const int kw1 = (ck ^ ((rk + 64) & 7)) * 8;
    const int vw0 = ((cv ^ (rv & 7)) & 15) * 8;     // XOR affects low 3 bits only
    const int vw1 = ((cv ^ ((rv + 32) & 7)) & 15) * 8;

    {   // prologue: stage macro-tile 0 (keys 0..127)
        int4 k0r = *(const int4*)(Kbh + (size_t)rk * HD + ck * 8);
        int4 k1r = *(const int4*)(Kbh + (size_t)(rk + 64) * HD + ck * 8);
        int4 v0r = *(const int4*)(Vbh + (size_t)rv * SEQ + cv * 8);
        int4 v1r = *(const int4*)(Vbh + (size_t)(rv + 32) * SEQ + cv * 8);
        *(int4*)&Ks[0][rk][kw0]      = k0r;
        *(int4*)&Ks[0][rk + 64][kw1] = k1r;
        *(int4*)&Vs[0][rv][vw0]      = v0r;
        *(int4*)&Vs[0][rv + 32][vw1] = v1r;
    }
    __syncthreads();

    for (int jt = 0; jt < niter; ++jt) {
        const int cur = jt & 1;
        const int j0 = jt << 7;
        int4 kn0, kn1, vn0, vn1;
        if (jt < niter - 1) {           // issue next macro-tile loads early
            int j1 = j0 + 128;
            kn0 = *(const int4*)(Kbh + (size_t)(j1 + rk) * HD + ck * 8);
            kn1 = *(const int4*)(Kbh + (size_t)(j1 + rk + 64) * HD + ck * 8);
            vn0 = *(const int4*)(Vbh + (size_t)rv * SEQ + j1 + cv * 8);
            vn1 = *(const int4*)(Vbh + (size_t)(rv + 32) * SEQ + j1 + cv * 8);
        }
        const u16 (*Kc)[64]  = Ks[cur];
        const u16 (*Vc)[128] = Vs[cur];
        #pragma unroll
        for (int hk = 0; hk < 2; ++hk) {
            const int j0h = j0 + hk * 64;
            if (j0h <= wrow0 + 31) {    // wave-uniform causal skip per half
                f32x4 s0[4], s1[4];
                __builtin_amdgcn_s_setprio(1);
                #pragma unroll
                for (int nt = 0; nt < 4; ++nt) {
                    const u16* krow = Kc[hk * 64 + nt * 16 + l15];
                    bf16x8 kf0 = *(const bf16x8*)&krow[(lg ^ sw) * 8];
                    bf16x8 kf1 = *(const bf16x8*)&krow[((4 + lg) ^ sw) * 8];
                    f32x4 a = zf;
                    a = __builtin_amdgcn_mfma_f32_16x16x32_bf16(kf0, qf00, a, 0, 0, 0);
                    a = __builtin_amdgcn_mfma_f32_16x16x32_bf16(kf1, qf01, a, 0, 0, 0);
                    s0[nt] = a;
                    f32x4 c2 = zf;
                    c2 = __builtin_amdgcn_mfma_f32_16x16x32_bf16(kf0, qf10, c2, 0, 0, 0);
                    c2 = __builtin_amdgcn_mfma_f32_16x16x32_bf16(kf1, qf11, c2, 0, 0, 0);
                    s1[nt] = c2;
                }
                __builtin_amdgcn_s_setprio(0);
                if (j0h + 63 > wrow0) { // diagonal region: per-element causal mask
                    #pragma unroll
                    for (int nt = 0; nt < 4; ++nt) {
                        int kb = j0h + nt * 16 + lg * 4;
                        #pragma unroll
                        for (int r = 0; r < 4; ++r) {
                            if (kb + r > wrow0 + l15)      s0[nt][r] = -INFINITY;
                            if (kb + r > wrow0 + 16 + l15) s1[nt][r] = -INFINITY;
                        }
                    }
                }
                float pm0 = fmaxf(fmaxf(vmax4(s0[0]), vmax4(s0[1])), fmaxf(vmax4(s0[2]), vmax4(s0[3])));
                float pm1 = fmaxf(fmaxf(vmax4(s1[0]), vmax4(s1[1])), fmaxf(vmax4(s1[2]), vmax4(s1[3])));
                pm0 = fmaxf(pm0, __shfl_xor(pm0, 16)); pm0 = fmaxf(pm0, __shfl_xor(pm0, 32));
                pm1 = fmaxf(pm1, __shfl_xor(pm1, 16)); pm1 = fmaxf(pm1, __shfl_xor(pm1, 32));
                if (!__all((pm0 <= mi0 + 8.f) && (pm1 <= mi1 + 8.f))) {
                    float mn0 = fmaxf(mi0, pm0), mn1 = fmaxf(mi1, pm1);
                    float so0 = __builtin_amdgcn_exp2f(mi0 - mn0);
                    float so1 = __builtin_amdgcn_exp2f(mi1 - mn1);
                    mi0 = mn0; mi1 = mn1;
                    li0 *= so0; li1 *= so1;
                    float a0 = __shfl(so0, lg * 4 + 0), a1 = __shfl(so0, lg * 4 + 1);
                    float a2 = __shfl(so0, lg * 4 + 2), a3 = __shfl(so0, lg * 4 + 3);
                    float b0_ = __shfl(so1, lg * 4 + 0), b1_ = __shfl(so1, lg * 4 + 1);
                    float b2_ = __shfl(so1, lg * 4 + 2), b3_ = __shfl(so1, lg * 4 + 3);
                    #pragma unroll
                    for (int d = 0; d < 4; ++d) {
                        acc0[d][0] *= a0;  acc0[d][1] *= a1;  acc0[d][2] *= a2;  acc0[d][3] *= a3;
                        acc1[d][0] *= b0_; acc1[d][1] *= b1_; acc1[d][2] *= b2_; acc1[d][3] *= b3_;
                    }
                }
                u32 dwa[8], dwb[8];
                float rs0 = 0.f, rs1 = 0.f;
                #pragma unroll
                for (int nt = 0; nt < 4; ++nt) {
                    float p0 = __builtin_amdgcn_exp2f(s0[nt][0] - mi0);
                    float p1 = __builtin_amdgcn_exp2f(s0[nt][1] - mi0);
                    float p2 = __builtin_amdgcn_exp2f(s0[nt][2] - mi0);
                    float p3 = __builtin_amdgcn_exp2f(s0[nt][3] - mi0);
                    rs0 += (p0 + p1) + (p2 + p3);
                    dwa[nt * 2] = pkbf(p0, p1); dwa[nt * 2 + 1] = pkbf(p2, p3);
                    float q0 = __builtin_amdgcn_exp2f(s1[nt][0] - mi1);
                    float q1 = __builtin_amdgcn_exp2f(s1[nt][1] - mi1);
                    float q2 = __builtin_amdgcn_exp2f(s1[nt][2] - mi1);
                    float q3 = __builtin_amdgcn_exp2f(s1[nt][3] - mi1);
                    rs1 += (q0 + q1) + (q2 + q3);
                    dwb[nt * 2] = pkbf(q0, q1); dwb[nt * 2 + 1] = pkbf(q2, q3);
                }
                rs0 += __shfl_xor(rs0, 16); rs0 += __shfl_xor(rs0, 32);
                rs1 += __shfl_xor(rs1, 16); rs1 += __shfl_xor(rs1, 32);
                li0 += rs0; li1 += rs1;
                bf16x8 pa00 = __builtin_bit_cast(bf16x8, make_int4((int)dwa[0], (int)dwa[1], (int)dwa[2], (int)dwa[3]));
                bf16x8 pa01 = __builtin_bit_cast(bf16x8, make_int4((int)dwa[4], (int)dwa[5], (int)dwa[6], (int)dwa[7]));
                bf16x8 pa10 = __builtin_bit_cast(bf16x8, make_int4((int)dwb[0], (int)dwb[1], (int)dwb[2], (int)dwb[3]));
                bf16x8 pa11 = __builtin_bit_cast(bf16x8, make_int4((int)dwb[4], (int)dwb[5], (int)dwb[6], (int)dwb[7]));
                // O += P V  (swizzled int2 V reads from half hk)
                const int o4 = (lg & 1) * 4, c0 = lg >> 1;
                __builtin_amdgcn_s_setprio(1);
                #pragma unroll
                for (int d = 0; d < 4; ++d) {
                    const u16* vrow = Vc[d * 16 + l15] + hk * 64;
                    int2 v0 = *(const int2*)(vrow + (((c0 + 0) ^ sw) * 8 + o4));
                    int2 v1 = *(const int2*)(vrow + (((c0 + 2) ^ sw) * 8 + o4));
                    int2 v2 = *(const int2*)(vrow + (((c0 + 4) ^ sw) * 8 + o4));
                    int2 v3 = *(const int2*)(vrow + (((c0 + 6) ^ sw) * 8 + o4));
                    bf16x8 vf0 = __builtin_bit_cast(bf16x8, make_int4(v0.x, v0.y, v1.x, v1.y));
                    bf16x8 vf1 = __builtin_bit_cast(bf16x8, make_int4(v2.x, v2.y, v3.x, v3.y));
                    acc0[d] = __builtin_amdgcn_mfma_f32_16x16x32_bf16(pa00, vf0, acc0[d], 0, 0, 0);
                    acc0[d] = __builtin_amdgcn_mfma_f32_16x16x32_bf16(pa01, vf1, acc0[d], 0, 0, 0);
                    acc1[d] = __builtin_amdgcn_mfma_f32_16x16x32_bf16(pa10, vf0, acc1[d], 0, 0, 0);
                    acc1[d] = __builtin_amdgcn_mfma_f32_16x16x32_bf16(pa11, vf1, acc1[d], 0, 0, 0);
                }
                __builtin_amdgcn_s_setprio(0);
            }
        }
        if (jt < niter - 1) {           // write-late into the other buffer
            *(int4*)&Ks[cur ^ 1][rk][kw0]      = kn0;
            *(int4*)&Ks[cur ^ 1][rk + 64][kw1] = kn1;
            *(int4*)&Vs[cur ^ 1][rv][vw0]      = vn0;
            *(int4*)&Vs[cur ^ 1][rv + 32][vw1] = vn1;
        }
        __syncthreads();
    }

    float e00 = 1.0f / __shfl(li0, lg * 4 + 0), e01 = 1.0f / __shfl(li0, lg * 4 + 1);
    float e02 = 1.0f / __shfl(li0, lg * 4 + 2), e03 = 1.0f / __shfl(li0, lg * 4 + 3);
    float e10 = 1.0f / __shfl(li1, lg * 4 + 0), e11 = 1.0f / __shfl(li1, lg * 4 + 1);
    float e12 = 1.0f / __shfl(li1, lg * 4 + 2), e13 = 1.0f / __shfl(li1, lg * 4 + 3);
    #pragma unroll
    for (int r = 0; r < 4; ++r) {
        float f0 = (r == 0) ? e00 : (r == 1) ? e01 : (r == 2) ? e02 : e03;
        float f1 = (r == 0) ? e10 : (r == 1) ? e11 : (r == 2) ? e12 : e13;
        int s0r = wrow0 + lg * 4 + r;
        size_t base0 = ((size_t)b * SEQ + s0r) * DM + h * HD;
        size_t base1 = ((size_t)b * SEQ + s0r + 16) * DM + h * HD;
        #pragma unroll
        for (int d = 0; d < 4; ++d) {
            ctx[base0 + d * 16 + l15] = f2bf(acc0[d][r] * f0);
            ctx[base1 + d * 16 + l15] = f2bf(acc1[d][r] * f1);
        }
    }
}

extern "C" void kernel_launch(void* const* d_in, const int* in_sizes, int n_in,
                              void* d_out, int out_size, void* d_ws, size_t ws_size,
                              hipStream_t stream) {
    const float* x  = (const float*)d_in[0];
    const float* Wq = (const float*)d_in[1];
    const float* bq = (const float*)d_in[2];
    const float* Wk = (const float*)d_in[3];
    const float* bk = (const float*)d_in[4];
    const float* Wv = (const float*)d_in[5];
    const float* bv = (const float*)d_in[6];
    const float* Wo = (const float*)d_in[7];
    const float* bo = (const float*)d_in[8];
    float* out = (float*)d_out;

    char* ws = (char*)d_ws;
    u16* xb  = (u16*)(ws);                    // 8192*768*2      = 12,582,912
    u16* Wt  = (u16*)(ws + 12582912);         // 2304*768*2      =  3,538,944
    u16* Wto = (u16*)(ws + 16121856);         // 768*768*2       =  1,179,648
    u16* Qw  = (u16*)(ws + 17301504);         // [BH][S][64]     = 12,582,912
    u16* Kw  = (u16*)(ws + 29884416);         // [BH][S][64]     = 12,582,912
    u16* Vtw = (u16*)(ws + 42467328);         // [BH][64][S]     = 12,582,912
    u16* ctx = (u16*)(ws + 55050240);         // [B][S][768]     = 12,582,912

    cvt_x<<<6144, 256, 0, stream>>>(x, xb, NTOK * DM / 4);
    dim3 tb(32, 8), tg4(24, 24, 4);
    transpose_w4<<<tg4, tb, 0, stream>>>(Wq, Wk, Wv, Wo, Wt, Wto);

    dim3 g2(32, 8);
    gemm_pipe<0><<<g2, 512, 0, stream>>>(xb, Wt, bq, bk, bv, Qw, Kw, Vtw, nullptr);
    attn_fwd<<<384, 512, 0, stream>>>(Qw, Kw, Vtw, ctx);
    dim3 g4(64, 4);
    gemm_pipe<1><<<g4, 512, 0, stream>>>(ctx, Wto, bo, nullptr, nullptr, nullptr, nullptr, nullptr, out);
}

// Round 12
// 121.047 us; speedup vs baseline: 1.2586x; 1.0458x over previous
//
#include <hip/hip_runtime.h>
#include <stdint.h>

#define DM    768
#define NH    12
#define HD    64
#define BATCH 4
#define SEQ   2048
#define NTOK  (BATCH*SEQ)   // 8192
#define NKT   12            // 768 / 64 K-tiles

typedef unsigned int   u32;
typedef unsigned short u16;
using bf16x8 = __attribute__((ext_vector_type(8))) short;
using f32x4  = __attribute__((ext_vector_type(4))) float;

// softmax runs in exp2 domain: Q pre-scaled by (1/8)*log2(e)
#define QSCALE 0.18033688011112042f

__device__ __forceinline__ u16 f2bf(float f) {
    u32 u = __float_as_uint(f);
    u = (u + 0x7FFFu + ((u >> 16) & 1u)) >> 16;
    return (u16)u;
}

__device__ __forceinline__ u32 pkbf(float a, float b) {
    u32 r;
    asm("v_cvt_pk_bf16_f32 %0, %1, %2" : "=v"(r) : "v"(a), "v"(b));
    return r;
}

template <int N>
__device__ __forceinline__ void waitvm() {
    if constexpr (N == 0)      asm volatile("s_waitcnt vmcnt(0)" ::: "memory");
    else if constexpr (N == 4) asm volatile("s_waitcnt vmcnt(4)" ::: "memory");
    else if constexpr (N == 5) asm volatile("s_waitcnt vmcnt(5)" ::: "memory");
    else if constexpr (N == 8) asm volatile("s_waitcnt vmcnt(8)" ::: "memory");
    else if constexpr (N == 9) asm volatile("s_waitcnt vmcnt(9)" ::: "memory");
    else static_assert(N == 0 || N == 4 || N == 5 || N == 8 || N == 9, "add literal");
}

__device__ __forceinline__ void gload_lds16(const void* gptr, void* ldsptr) {
    __builtin_amdgcn_global_load_lds(
        (__attribute__((address_space(1))) const u32*)gptr,
        (__attribute__((address_space(3))) u32*)ldsptr, 16, 0, 0);
}

__device__ __forceinline__ float vmax4(f32x4 v) {
    return fmaxf(fmaxf(v[0], v[1]), fmaxf(v[2], v[3]));
}

// ---------------- x fp32 -> bf16 (vectorized) ----------------
__global__ void cvt_x(const float* __restrict__ x, u16* __restrict__ xb, int n4) {
    int i = blockIdx.x * blockDim.x + threadIdx.x;
    if (i >= n4) return;
    float4 v = ((const float4*)x)[i];
    ushort4 o;
    o.x = f2bf(v.x); o.y = f2bf(v.y); o.z = f2bf(v.z); o.w = f2bf(v.w);
    ((ushort4*)xb)[i] = o;
}

// ------- all 4 weight transposes in ONE launch: W [k][n] fp32 -> Wt [n][k] bf16 -------
__global__ void transpose_w4(const float* __restrict__ q, const float* __restrict__ k,
                             const float* __restrict__ v, const float* __restrict__ o,
                             u16* __restrict__ Wt, u16* __restrict__ Wto) {
    __shared__ float tile[32][33];
    int z = blockIdx.z;
    const float* W = (z == 0) ? q : (z == 1) ? k : (z == 2) ? v : o;
    u16* D = (z < 3) ? (Wt + (size_t)z * DM * DM) : Wto;
    int tx = threadIdx.x, ty = threadIdx.y;   // 32 x 8
    int x0 = blockIdx.x * 32, y0 = blockIdx.y * 32;
    #pragma unroll
    for (int i = 0; i < 32; i += 8)
        tile[ty + i][tx] = W[(size_t)(y0 + ty + i) * DM + x0 + tx];
    __syncthreads();
    #pragma unroll
    for (int i = 0; i < 32; i += 8)
        D[(size_t)(x0 + ty + i) * DM + y0 + tx] = f2bf(tile[tx][ty + i]);
}

// ---- bf16 MFMA GEMM, BK=64, 2-tiles-ahead pipeline with counted vmcnt (T3/T4) ----
// (unchanged — MODE0 grid 32x8=256 blocks, MODE1 64x4=256 blocks)
template <int MODE>
__global__ __launch_bounds__(512, 2)
void gemm_pipe(const u16* __restrict__ A, const u16* __restrict__ Bt,
               const float* __restrict__ b0, const float* __restrict__ b1,
               const float* __restrict__ b2,
               u16* __restrict__ Qo, u16* __restrict__ Ko, u16* __restrict__ Vto,
               float* __restrict__ Out)
{
    constexpr int BM = (MODE == 0) ? 256 : 128;
    constexpr int BN = (MODE == 0) ? 288 : 192;
    constexpr int MF = 4;
    constexpr int NF = (MODE == 0) ? 9 : 3;
    constexpr int AL = BM / 64;
    constexpr int BFULL = (MODE == 0) ? 4 : 3;

    __shared__ u16 As[2][BM][64];
    __shared__ u16 Bs[2][BN][64];

    const int t = threadIdx.x;
    const int w = t >> 6, l = t & 63;
    const int l15 = l & 15, lg = l >> 4;
    const int m0 = blockIdx.x * BM;
    const int n0 = blockIdx.y * BN;
    const int waveM = ((MODE == 0) ? (w >> 1) : (w >> 2)) * 64;
    const int waveN = (MODE == 0) ? (w & 1) * 144 : (w & 3) * 48;

    f32x4 zf = {0.f, 0.f, 0.f, 0.f};
    f32x4 acc[MF][NF];
    #pragma unroll
    for (int i = 0; i < MF; ++i)
        #pragma unroll
        for (int j = 0; j < NF; ++j) acc[i][j] = zf;

    const u16* Arow0 = A  + (size_t)m0 * DM;
    const u16* Brow0 = Bt + (size_t)n0 * DM;

    auto stage = [&](int d, int k0) {
        #pragma unroll
        for (int i = 0; i < AL; ++i) {
            int f = i * 512 + t;
            int row = f >> 3, c = f & 7;
            int gc = c ^ (row & 7);
            gload_lds16(Arow0 + (size_t)row * DM + k0 + gc * 8, &As[d][row][c * 8]);
        }
        #pragma unroll
        for (int i = 0; i < BFULL; ++i) {
            int f = i * 512 + t;
            int row = f >> 3, c = f & 7;
            int gc = c ^ (row & 7);
            gload_lds16(Brow0 + (size_t)row * DM + k0 + gc * 8, &Bs[d][row][c * 8]);
        }
        if constexpr (MODE == 0) {
            if (t < 256) {
                int f = 2048 + t;
                int row = f >> 3, c = f & 7;
                int gc = c ^ (row & 7);
                gload_lds16(Brow0 + (size_t)row * DM + k0 + gc * 8, &Bs[d][row][c * 8]);
            }
        }
    };
    auto wait_tile = [&]() {
        if constexpr (MODE == 0) {
            if (w < 4) waitvm<9>(); else waitvm<8>();
        } else {
            waitvm<5>();
        }
    };
    auto phase = [&](int d, int kk) {
        const int ch = ((kk * 4 + lg) ^ (l15 & 7)) * 8;
        bf16x8 af[MF], bfr[NF];
        #pragma unroll
        for (int m = 0; m < MF; ++m)
            af[m] = *(const bf16x8*)&As[d][waveM + m * 16 + l15][ch];
        #pragma unroll
        for (int n = 0; n < NF; ++n)
            bfr[n] = *(const bf16x8*)&Bs[d][waveN + n * 16 + l15][ch];
        __builtin_amdgcn_s_setprio(1);
        #pragma unroll
        for (int m = 0; m < MF; ++m)
            #pragma unroll
            for (int n = 0; n < NF; ++n)
                acc[m][n] = __builtin_amdgcn_mfma_f32_16x16x32_bf16(af[m], bfr[n], acc[m][n], 0, 0, 0);
        __builtin_amdgcn_s_setprio(0);
    };

    stage(0, 0);
    stage(1, 64);

    for (int tt = 0; tt < NKT - 1; ++tt) {
        const int c = tt & 1;
        wait_tile();
        __builtin_amdgcn_s_barrier();
        __builtin_amdgcn_sched_barrier(0);
        phase(c, 0);
        phase(c, 1);
        __builtin_amdgcn_sched_barrier(0);
        __builtin_amdgcn_s_barrier();
        __builtin_amdgcn_sched_barrier(0);
        if (tt + 2 < NKT) stage(c, (tt + 2) * 64);
    }
    {
        waitvm<0>();
        __builtin_amdgcn_s_barrier();
        __builtin_amdgcn_sched_barrier(0);
        phase((NKT - 1) & 1, 0);
        phase((NKT - 1) & 1, 1);
    }

    if (MODE == 1) {
        #pragma unroll
        for (int m = 0; m < MF; ++m) {
            int grow = m0 + waveM + m * 16 + lg * 4;
            #pragma unroll
            for (int n = 0; n < NF; ++n) {
                int gcol = n0 + waveN + n * 16 + l15;
                float bias = b0[gcol];
                #pragma unroll
                for (int r = 0; r < 4; ++r)
                    Out[(size_t)(grow + r) * DM + gcol] = acc[m][n][r] + bias;
            }
        }
    } else {
        #pragma unroll
        for (int m = 0; m < MF; ++m) {
            int grow = m0 + waveM + m * 16 + lg * 4;
            int bb = grow >> 11, ss = grow & 2047;
            #pragma unroll
            for (int n = 0; n < NF; ++n) {
                int nstart = n0 + waveN + n * 16;
                int which = nstart / DM;
                int cbase = nstart - which * DM + l15;
                int h = cbase >> 6, hd = cbase & 63;
                if (which == 0) {
                    float bias = b0[cbase];
                    #pragma unroll
                    for (int r = 0; r < 4; ++r)
                        Qo[(((size_t)bb * NH + h) * SEQ + (ss + r)) * HD + hd] =
                            f2bf((acc[m][n][r] + bias) * QSCALE);
                } else if (which == 1) {
                    float bias = b1[cbase];
                    #pragma unroll
                    for (int r = 0; r < 4; ++r)
                        Ko[(((size_t)bb * NH + h) * SEQ + (ss + r)) * HD + hd] =
                            f2bf(acc[m][n][r] + bias);
                } else {
                    float bias = b2[cbase];
                    u32 lo = pkbf(acc[m][n][0] + bias, acc[m][n][1] + bias);
                    u32 hi = pkbf(acc[m][n][2] + bias, acc[m][n][3] + bias);
                    *(int2*)&Vto[(((size_t)bb * NH + h) * HD + hd) * SEQ + ss] =
                        make_int2((int)lo, (int)hi);
                }
            }
        }
    }
}

// ---------------- causal flash attention v6 ----------------
// 128-row strips (8 waves x 16 rows, ONE q-col frag/wave), grid 768 blocks:
// 256 blocks queued behind the 512 residency slots -> greedy LPT balance +
// sustained 2 blocks/CU. K/V staged via global_load_lds with pre-swizzled
// source (linear LDS dest, swizzled reads — rule #21), counted vmcnt(4)
// with next 128-key macro-tile always in flight. LDS 64KB dbuf.
__global__ __launch_bounds__(512, 4)
void attn_fwd(const u16* __restrict__ Q, const u16* __restrict__ K_,
              const u16* __restrict__ Vt, u16* __restrict__ ctx)
{
    __shared__ u16 Ks[2][128][64];      // [key][d]
    __shared__ u16 Vs[2][64][128];      // [d][key]

    const int t = threadIdx.x, w = t >> 6, l = t & 63;
    const int l15 = l & 15, lg = l >> 4;
    const int sw = l15 & 7;             // read-side swizzle key
    const int bx = blockIdx.x;
    const int ord = bx / 48;            // ascending => q16 descending (LPT dispatch)
    const int bh  = bx - ord * 48;
    const int q16 = 15 - ord;           // 128-row strip index
    const int b = bh / NH, h = bh - b * NH;
    const int wrow0 = q16 * 128 + w * 16;
    const int niter = q16 + 1;          // 128-key macro-tiles

    const u16* Qp = Q + ((size_t)bh * SEQ + wrow0 + l15) * HD;
    bf16x8 qf0 = *(const bf16x8*)(Qp + lg * 8);
    bf16x8 qf1 = *(const bf16x8*)(Qp + 32 + lg * 8);

    f32x4 zf = {0.f, 0.f, 0.f, 0.f};
    f32x4 acc[4];
    #pragma unroll
    for (int d = 0; d < 4; ++d) acc[d] = zf;
    float mi = -INFINITY, li = 0.f;

    const u16* Kbh = K_ + (size_t)bh * SEQ * HD;
    const u16* Vbh = Vt + (size_t)bh * HD * SEQ;

    // stage one 128-key macro-tile into buffer d via global_load_lds:
    // K: chunk f (0..1023): row=f>>3, c=f&7, src chunk c^(row&7)  [linear dest]
    // V: chunk f (0..1023): r=f>>4, c=f&15, src chunk (c&8)|((c^r)&7)
    auto stage = [&](int d, int j0) {
        #pragma unroll
        for (int i = 0; i < 2; ++i) {
            int f = i * 512 + t;
            int row = f >> 3, c = f & 7;
            gload_lds16(Kbh + (size_t)(j0 + row) * HD + (c ^ (row & 7)) * 8,
                        (u16*)Ks[d] + (size_t)f * 8);
        }
        #pragma unroll
        for (int i = 0; i < 2; ++i) {
            int f = i * 512 + t;
            int r = f >> 4, c = f & 15;
            gload_lds16(Vbh + (size_t)r * SEQ + j0 + (((c & 8) | ((c ^ r) & 7))) * 8,
                        (u16*)Vs[d] + (size_t)f * 8);
        }
    };

    stage(0, 0);
    stage(1, 128);                      // keys 128..255 always exist (S=2048)

    for (int jt = 0; jt < niter; ++jt) {
        const int cur = jt & 1;
        const int j0 = jt << 7;
        if (jt < niter - 1) waitvm<4>(); else waitvm<0>();
        __builtin_amdgcn_s_barrier();
        __builtin_amdgcn_sched_barrier(0);
        const u16 (*Kc)[64]  = Ks[cur];
        const u16 (*Vc)[128] = Vs[cur];
        #pragma unroll
        for (int hk = 0; hk < 2; ++hk) {
            const int j0h = j0 + hk * 64;
            if (j0h <= wrow0 + 15) {    // wave-uniform causal skip per half
                f32x4 s0[4];
                __builtin_amdgcn_s_setprio(1);
                #pragma unroll
                for (int nt = 0; nt < 4; ++nt) {
                    const u16* krow = Kc[hk * 64 + nt * 16 + l15];
                    bf16x8 kf0 = *(const bf16x8*)&krow[(lg ^ sw) * 8];
                    bf16x8 kf1 = *(const bf16x8*)&krow[((4 + lg) ^ sw) * 8];
                    f32x4 a = zf;
                    a = __builtin_amdgcn_mfma_f32_16x16x32_bf16(kf0, qf0, a, 0, 0, 0);
                    a = __builtin_amdgcn_mfma_f32_16x16x32_bf16(kf1, qf1, a, 0, 0, 0);
                    s0[nt] = a;
                }
                __builtin_amdgcn_s_setprio(0);
                if (j0h + 63 > wrow0) { // diagonal region: per-element causal mask
                    #pragma unroll
                    for (int nt = 0; nt < 4; ++nt) {
                        int kb = j0h + nt * 16 + lg * 4;
                        #pragma unroll
                        for (int r = 0; r < 4; ++r)
                            if (kb + r > wrow0 + l15) s0[nt][r] = -INFINITY;
                    }
                }
                float pm = fmaxf(fmaxf(vmax4(s0[0]), vmax4(s0[1])), fmaxf(vmax4(s0[2]), vmax4(s0[3])));
                pm = fmaxf(pm, __shfl_xor(pm, 16));
                pm = fmaxf(pm, __shfl_xor(pm, 32));
                if (!__all(pm <= mi + 8.f)) {   // defer-max (T13)
                    float mn = fmaxf(mi, pm);
                    float so = __builtin_amdgcn_exp2f(mi - mn);
                    mi = mn;
                    li *= so;
                    float a0 = __shfl(so, lg * 4 + 0), a1 = __shfl(so, lg * 4 + 1);
                    float a2 = __shfl(so, lg * 4 + 2), a3 = __shfl(so, lg * 4 + 3);
                    #pragma unroll
                    for (int d = 0; d < 4; ++d) {
                        acc[d][0] *= a0; acc[d][1] *= a1;
                        acc[d][2] *= a2; acc[d][3] *= a3;
                    }
                }
                u32 dwa[8];
                float rs = 0.f;
                #pragma unroll
                for (int nt = 0; nt < 4; ++nt) {
                    float p0 = __builtin_amdgcn_exp2f(s0[nt][0] - mi);
                    float p1 = __builtin_amdgcn_exp2f(s0[nt][1] - mi);
                    float p2 = __builtin_amdgcn_exp2f(s0[nt][2] - mi);
                    float p3 = __builtin_amdgcn_exp2f(s0[nt][3] - mi);
                    rs += (p0 + p1) + (p2 + p3);
                    dwa[nt * 2] = pkbf(p0, p1); dwa[nt * 2 + 1] = pkbf(p2, p3);
                }
                rs += __shfl_xor(rs, 16);
                rs += __shfl_xor(rs, 32);
                li += rs;
                bf16x8 pa0 = __builtin_bit_cast(bf16x8, make_int4((int)dwa[0], (int)dwa[1], (int)dwa[2], (int)dwa[3]));
                bf16x8 pa1 = __builtin_bit_cast(bf16x8, make_int4((int)dwa[4], (int)dwa[5], (int)dwa[6], (int)dwa[7]));
                // O += P V  (swizzled int2 V reads from half hk)
                const int o4 = (lg & 1) * 4, c0 = lg >> 1;
                __builtin_amdgcn_s_setprio(1);
                #pragma unroll
                for (int d = 0; d < 4; ++d) {
                    const u16* vrow = Vc[d * 16 + l15] + hk * 64;
                    int2 v0 = *(const int2*)(vrow + (((c0 + 0) ^ sw) * 8 + o4));
                    int2 v1 = *(const int2*)(vrow + (((c0 + 2) ^ sw) * 8 + o4));
                    int2 v2 = *(const int2*)(vrow + (((c0 + 4) ^ sw) * 8 + o4));
                    int2 v3 = *(const int2*)(vrow + (((c0 + 6) ^ sw) * 8 + o4));
                    bf16x8 vf0 = __builtin_bit_cast(bf16x8, make_int4(v0.x, v0.y, v1.x, v1.y));
                    bf16x8 vf1 = __builtin_bit_cast(bf16x8, make_int4(v2.x, v2.y, v3.x, v3.y));
                    acc[d] = __builtin_amdgcn_mfma_f32_16x16x32_bf16(pa0, vf0, acc[d], 0, 0, 0);
                    acc[d] = __builtin_amdgcn_mfma_f32_16x16x32_bf16(pa1, vf1, acc[d], 0, 0, 0);
                }
                __builtin_amdgcn_s_setprio(0);
            }
        }
        if (jt < niter - 1) {
            __builtin_amdgcn_s_barrier();            // all waves done reading buf cur
            __builtin_amdgcn_sched_barrier(0);
            if (jt + 2 < niter) stage(cur, (jt + 2) << 7);
        }
    }

    // epilogue: ctx [B][S][768] bf16
    float e0 = 1.0f / __shfl(li, lg * 4 + 0), e1 = 1.0f / __shfl(li, lg * 4 + 1);
    float e2 = 1.0f / __shfl(li, lg * 4 + 2), e3 = 1.0f / __shfl(li, lg * 4 + 3);
    #pragma unroll
    for (int r = 0; r < 4; ++r) {
        float f0 = (r == 0) ? e0 : (r == 1) ? e1 : (r == 2) ? e2 : e3;
        int s = wrow0 + lg * 4 + r;
        size_t base = ((size_t)b * SEQ + s) * DM + h * HD;
        #pragma unroll
        for (int d = 0; d < 4; ++d)
            ctx[base + d * 16 + l15] = f2bf(acc[d][r] * f0);
    }
}

extern "C" void kernel_launch(void* const* d_in, const int* in_sizes, int n_in,
                              void* d_out, int out_size, void* d_ws, size_t ws_size,
                              hipStream_t stream) {
    const float* x  = (const float*)d_in[0];
    const float* Wq = (const float*)d_in[1];
    const float* bq = (const float*)d_in[2];
    const float* Wk = (const float*)d_in[3];
    const float* bk = (const float*)d_in[4];
    const float* Wv = (const float*)d_in[5];
    const float* bv = (const float*)d_in[6];
    const float* Wo = (const float*)d_in[7];
    const float* bo = (const float*)d_in[8];
    float* out = (float*)d_out;

    char* ws = (char*)d_ws;
    u16* xb  = (u16*)(ws);                    // 8192*768*2      = 12,582,912
    u16* Wt  = (u16*)(ws + 12582912);         // 2304*768*2      =  3,538,944
    u16* Wto = (u16*)(ws + 16121856);         // 768*768*2       =  1,179,648
    u16* Qw  = (u16*)(ws + 17301504);         // [BH][S][64]     = 12,582,912
    u16* Kw  = (u16*)(ws + 29884416);         // [BH][S][64]     = 12,582,912
    u16* Vtw = (u16*)(ws + 42467328);         // [BH][64][S]     = 12,582,912
    u16* ctx = (u16*)(ws + 55050240);         // [B][S][768]     = 12,582,912

    cvt_x<<<6144, 256, 0, stream>>>(x, xb, NTOK * DM / 4);
    dim3 tb(32, 8), tg4(24, 24, 4);
    transpose_w4<<<tg4, tb, 0, stream>>>(Wq, Wk, Wv, Wo, Wt, Wto);

    dim3 g2(32, 8);
    gemm_pipe<0><<<g2, 512, 0, stream>>>(xb, Wt, bq, bk, bv, Qw, Kw, Vtw, nullptr);
    attn_fwd<<<768, 512, 0, stream>>>(Qw, Kw, Vtw, ctx);
    dim3 g4(64, 4);
    gemm_pipe<1><<<g4, 512, 0, stream>>>(ctx, Wto, bo, nullptr, nullptr, nullptr, nullptr, nullptr, out);
}